// Round 11
// baseline (289.143 us; speedup 1.0000x reference)
//
#include <hip/hip_runtime.h>

typedef unsigned short u16;
typedef __bf16 bf16_t;
typedef bf16_t bf16x8 __attribute__((ext_vector_type(8)));
typedef u16 u16x8 __attribute__((ext_vector_type(8)));
typedef float f32x4 __attribute__((ext_vector_type(4)));

#define DEVI __device__ __forceinline__

// B=2, S=1024, E=1024, H=16, DH=64, MAXLEN=2048, table=4095

DEVI u16 f2bf(float f) {
    unsigned u = __builtin_bit_cast(unsigned, f);
    u = (u + 0x7FFFu + ((u >> 16) & 1u)) >> 16;
    return (u16)u;
}
DEVI float bf2f(u16 b) {
    unsigned u = ((unsigned)b) << 16;
    return __builtin_bit_cast(float, u);
}
DEVI f32x4 mfma16(u16x8 a, u16x8 b, f32x4 c) {
    return __builtin_amdgcn_mfma_f32_16x16x32_bf16(
        __builtin_bit_cast(bf16x8, a), __builtin_bit_cast(bf16x8, b), c, 0, 0, 0);
}
// async global->LDS, 16B per lane; LDS dest = base + lane*16 (wave-uniform base)
DEVI void gl2lds(const u16* g, u16* l) {
    __builtin_amdgcn_global_load_lds(
        (__attribute__((address_space(1))) void*)g,
        (__attribute__((address_space(3))) void*)l, 16, 0, 0);
}

// ---------------- convert fp32 -> bf16 (query,key,value,emb) ----------------
__global__ __launch_bounds__(256) void cvt_kernel(
    const float* __restrict__ q, const float* __restrict__ k, const float* __restrict__ v,
    const float* __restrict__ emb,
    u16* __restrict__ xq, u16* __restrict__ xk, u16* __restrict__ xv, u16* __restrict__ embb)
{
    const long NQ = 2097152;   // 2*1024*1024
    const long NE = 262080;    // 4095*64
    long i4 = ((long)blockIdx.x * 256 + threadIdx.x) * 4;
    if (i4 < 3 * NQ) {
        int which = (int)(i4 >> 21);
        long off = i4 & (NQ - 1);
        const float* src = which == 0 ? q : (which == 1 ? k : v);
        u16* dst = which == 0 ? xq : (which == 1 ? xk : xv);
        float4 f = *(const float4*)(src + off);
        ushort4 o; o.x = f2bf(f.x); o.y = f2bf(f.y); o.z = f2bf(f.z); o.w = f2bf(f.w);
        *(ushort4*)(dst + off) = o;
    } else {
        long off = i4 - 3 * NQ;
        if (off < NE) {
            float4 f = *(const float4*)(emb + off);
            ushort4 o; o.x = f2bf(f.x); o.y = f2bf(f.y); o.z = f2bf(f.z); o.w = f2bf(f.w);
            *(ushort4*)(embb + off) = o;
        }
    }
}

// ---------------- W [K][N] fp32 -> WT [N][K] bf16 (tiled transpose) ---------
__global__ __launch_bounds__(256) void wt_kernel(
    const float* __restrict__ w0, const float* __restrict__ w1,
    const float* __restrict__ w2, const float* __restrict__ w3,
    u16* __restrict__ t0, u16* __restrict__ t1, u16* __restrict__ t2, u16* __restrict__ t3)
{
    int z = blockIdx.z;
    const float* W = z == 0 ? w0 : (z == 1 ? w1 : (z == 2 ? w2 : w3));
    u16* T = z == 0 ? t0 : (z == 1 ? t1 : (z == 2 ? t2 : t3));
    __shared__ float tile[64][65];
    int k0 = blockIdx.y * 64, n0 = blockIdx.x * 64;
    int tx = threadIdx.x, ty = threadIdx.y;   // (64,4)
    for (int r = ty; r < 64; r += 4)
        tile[r][tx] = W[(long)(k0 + r) * 1024 + n0 + tx];
    __syncthreads();
    for (int r = ty; r < 64; r += 4)
        T[(long)(n0 + r) * 1024 + k0 + tx] = f2bf(tile[tx][r]);
}

// ---------------- bf16 MFMA GEMM, dbuf global_load_lds, BK=64, XCD swizzle --
// C tile (MT*32) x 128; A[M][1024], WT[N][1024] (both row-major K)
// Per buf: two 32-k half-tiles [half][row][32 u16], chunk (8 u16) swizzle
// pos p = c ^ ((row>>1)&3) within each half.  16 K-iterations (BK=64) ->
// half the barriers of the BK=32 version; same total load/MFMA counts.
// Grid (8, GY, z), GY % 4 == 0.  XCD swizzle: per-XCD 4 x-tiles x GY/4 y-tiles.
// mode 0: q-proj ((acc+b)*0.125 -> qb); 1: k-proj -> kb; 2: v-proj -> vT;
// mode 3: out-proj -> fp32 [M][N]
template<int MT>
__global__ __launch_bounds__(256) void gemm_kernel(
    const u16* __restrict__ A0, const u16* __restrict__ A1, const u16* __restrict__ A2,
    const u16* __restrict__ W0, const u16* __restrict__ W1, const u16* __restrict__ W2,
    const float* __restrict__ bias0, const float* __restrict__ bias1, const float* __restrict__ bias2,
    u16* __restrict__ o0, u16* __restrict__ o1, u16* __restrict__ o2,
    float* __restrict__ ofp, int mode_base)
{
    int z = blockIdx.z;
    int mode = mode_base + z;
    const u16* A = z == 0 ? A0 : (z == 1 ? A1 : A2);
    const u16* W = z == 0 ? W0 : (z == 1 ? W1 : W2);
    const float* bias = z == 0 ? bias0 : (z == 1 ? bias1 : bias2);
    u16* ob = z == 0 ? o0 : (z == 1 ? o1 : o2);

    constexpr int MROWS = MT * 32;
    __shared__ u16 la[2 * 2 * MROWS * 32];   // [buf][half][row][32]
    __shared__ u16 lw[2 * 2 * 128 * 32];

    // XCD-aware bijective swizzle for (8, GY) grids
    int lin = blockIdx.x + (blockIdx.y << 3);
    int xcd = lin & 7, idx = lin >> 3;
    int gy4 = gridDim.y >> 2;
    int xt = (xcd & 1) * 4 + (idx & 3);
    int yt = (xcd >> 1) * gy4 + (idx >> 2);
    int m0 = yt * MROWS, n0 = xt * 128;

    int t = threadIdx.x, lane = t & 63, wid = t >> 6;
    int l15 = lane & 15, quad = lane >> 4;
    int wm = (wid >> 1) * (MT * 16), wn = (wid & 1) * 64;
    int sr = lane >> 2, sp = lane & 3;   // staging: 16 rows x 4 chunks per instr

    f32x4 acc[MT][4] = {};

    auto stage_half = [&](int buf, int half, int k0) {
#pragma unroll
        for (int q = 0; q < MT / 2; q++) {
            int r = wid * (MT * 8) + q * 16 + sr;
            int c = sp ^ ((r >> 1) & 3);
            gl2lds(A + (long)(m0 + r) * 1024 + k0 + c * 8,
                   la + (buf * 2 + half) * (MROWS * 32) + (wid * (MT * 8) + q * 16) * 32);
        }
#pragma unroll
        for (int q = 0; q < 2; q++) {
            int r = wid * 32 + q * 16 + sr;
            int c = sp ^ ((r >> 1) & 3);
            gl2lds(W + (long)(n0 + r) * 1024 + k0 + c * 8,
                   lw + (buf * 2 + half) * (128 * 32) + (wid * 32 + q * 16) * 32);
        }
    };
    auto stage = [&](int buf, int k0) {
        stage_half(buf, 0, k0);
        stage_half(buf, 1, k0 + 32);
    };

    stage(0, 0);
    __syncthreads();
    int cur = 0;
#pragma unroll 1
    for (int k0 = 0; k0 < 1024; k0 += 64) {
        if (k0 < 960) stage(cur ^ 1, k0 + 64);   // prefetch next K-step (in flight during compute)
#pragma unroll
        for (int h = 0; h < 2; h++) {
            const u16* lab = la + (cur * 2 + h) * (MROWS * 32);
            const u16* lwb = lw + (cur * 2 + h) * (128 * 32);
            u16x8 af[MT], bfr[4];
#pragma unroll
            for (int mt = 0; mt < MT; mt++) {
                int r = wm + mt * 16 + l15;
                af[mt] = *(const u16x8*)&lab[r * 32 + ((quad ^ ((r >> 1) & 3)) * 8)];
            }
#pragma unroll
            for (int nt = 0; nt < 4; nt++) {
                int r = wn + nt * 16 + l15;
                bfr[nt] = *(const u16x8*)&lwb[r * 32 + ((quad ^ ((r >> 1) & 3)) * 8)];
            }
#pragma unroll
            for (int mt = 0; mt < MT; mt++)
#pragma unroll
                for (int nt = 0; nt < 4; nt++)
                    acc[mt][nt] = mfma16(af[mt], bfr[nt], acc[mt][nt]);
        }
        __syncthreads();   // drains vmcnt (next buf staged) + lgkm; one barrier per 64-k
        cur ^= 1;
    }

#pragma unroll
    for (int mt = 0; mt < MT; mt++)
#pragma unroll
        for (int nt = 0; nt < 4; nt++)
#pragma unroll
            for (int reg = 0; reg < 4; reg++) {
                int gm = m0 + wm + mt * 16 + quad * 4 + reg;   // C row = quad*4+reg
                int gn = n0 + wn + nt * 16 + l15;              // C col = lane&15
                float val = acc[mt][nt][reg] + bias[gn];
                if (mode == 0) {
                    val *= 0.125f;   // 1/sqrt(DH)
                    long o = ((long)((gm >> 10) * 16 + (gn >> 6)) << 16) + ((gm & 1023) << 6) + (gn & 63);
                    ob[o] = f2bf(val);
                } else if (mode == 1) {
                    long o = ((long)((gm >> 10) * 16 + (gn >> 6)) << 16) + ((gm & 1023) << 6) + (gn & 63);
                    ob[o] = f2bf(val);
                } else if (mode == 2) {
                    long o = ((long)((gm >> 10) * 16 + (gn >> 6)) << 16) + ((long)(gn & 63) << 10) + (gm & 1023);
                    ob[o] = f2bf(val);
                } else {
                    ofp[(long)gm * 1024 + gn] = val;
                }
            }
}

// ---------------- Gc skewed GEMM -> SKEW-SPACE table Bskew ------------------
// Bskew[u][cc] = q[u] . emb[1024 + i_u + cc] + (cc<=i_u ? rpb[cc+2047] : rpb[cc+1022])
// (i_u = u & 1023, cc in [0,1023]).  Consumed by flash:
//   j <= i   : rel+rpb = Bskew[i][i-j]
//   j == i+1 : rel+rpb = rpb[2046]
//   j >= i+2 : rel+rpb = Bskew[i+1][i+1025-j]
__global__ __launch_bounds__(256) void gc_kernel(
    const u16* __restrict__ qb, const u16* __restrict__ embb,
    const float* __restrict__ rpb, u16* __restrict__ Bskew)
{
    int u0 = blockIdx.x * 32;
    int i0 = u0 & 1023;
    int t = threadIdx.x, lane = t & 63, wid = t >> 6;
    int l15 = lane & 15, quad = lane >> 4;

    __shared__ float lds_rpb[2048];   // [cc]=rpb[cc+2047], [1024+cc]=rpb[cc+1022]
    for (int j = t; j < 1024; j += 256) {
        lds_rpb[j] = rpb[j + 2047];
        lds_rpb[1024 + j] = rpb[j + 1022];
    }
    __syncthreads();

    // A fragments: rows u0 .. u0+31 (2 row-groups of 16)
    u16x8 aq[2][2];
#pragma unroll
    for (int rg = 0; rg < 2; rg++) {
        long qoff = (long)(u0 + rg * 16 + l15) * 64 + quad * 8;
        aq[rg][0] = *(const u16x8*)&qb[qoff];
        aq[rg][1] = *(const u16x8*)&qb[qoff + 32];
    }

    // prefetch first emb tile for this wave
    u16x8 nb0, nb1;
    {
        long ebase = (long)(1024 + i0 + wid * 16 + l15) * 64 + quad * 8;
        nb0 = *(const u16x8*)&embb[ebase];
        nb1 = *(const u16x8*)&embb[ebase + 32];
    }

    // w-tiles 0..65 cover w in [0,1056); max needed w = 1023+31 = 1054
    for (int tt = wid; tt < 66; tt += 4) {
        u16x8 b0 = nb0, b1 = nb1;
        if (tt + 4 < 66) {
            long ebase = (long)(1024 + i0 + (tt + 4) * 16 + l15) * 64 + quad * 8;
            nb0 = *(const u16x8*)&embb[ebase];
            nb1 = *(const u16x8*)&embb[ebase + 32];
        }
        int w0 = tt * 16;
#pragma unroll
        for (int rg = 0; rg < 2; rg++) {
            f32x4 c = {};
            c = mfma16(aq[rg][0], b0, c);
            c = mfma16(aq[rg][1], b1, c);
#pragma unroll
            for (int reg = 0; reg < 4; reg++) {
                int row = rg * 16 + quad * 4 + reg;
                int cc = w0 + l15 - row;
                if ((unsigned)cc <= 1023u) {
                    int i = i0 + row;
                    float rb = lds_rpb[cc + ((cc <= i) ? 0 : 1024)];
                    Bskew[((long)(u0 + row) << 10) + cc] = f2bf(c[reg] + rb);
                }
            }
        }
    }
}

// ---------------- flash attention (j-split x2, dbuf K/V @ 40960B LDS) -------
// r10-verified structure + T5 setprio around MFMA clusters + T13 defer-max
// (THR=8, numerically exact: skips rescale when max growth small).
__global__ __launch_bounds__(256, 4) void flash_kernel(
    const u16* __restrict__ qb, const u16* __restrict__ kb, const u16* __restrict__ vT,
    const u16* __restrict__ Bskew, const float* __restrict__ rpb,
    float* __restrict__ Po, float* __restrict__ Pm, float* __restrict__ Pl)
{
    int itile = blockIdx.x;        // 0..15
    int bh = blockIdx.y;           // 0..31
    int js = blockIdx.z;           // 0..1
    int t = threadIdx.x, lane = t & 63, wid = t >> 6;
    int l15 = lane & 15, quad = lane >> 4;
    int i0w = itile * 64 + wid * 16;

    __shared__ u16 lds_k[2][64 * 64];  // [j][d]
    __shared__ u16 lds_v[2][64 * 64];  // [d][j]
    __shared__ u16 lds_p[4][1024];     // per-wave P, chunk-swizzled, no pad

    int sr8 = lane >> 3, sp8 = lane & 7;   // staging: 8 rows x 8 chunks per instr

    float rpb2046 = rpb[2046];

    u16x8 aq[2];
    {
        long qoff = ((long)(bh * 1024) + i0w + l15) * 64 + quad * 8;
        aq[0] = *(const u16x8*)&qb[qoff];
        aq[1] = *(const u16x8*)&qb[qoff + 32];
    }
    float m_r[4], l_r[4];
    f32x4 o_acc[4] = {};
#pragma unroll
    for (int r = 0; r < 4; r++) { m_r[r] = -1e30f; l_r[r] = 0.f; }

    const u16* kbase = kb + (long)bh * 65536;
    const u16* vbase = vT + (long)bh * 65536;
    const u16* bbase = Bskew + ((long)bh << 20);

    auto stage = [&](int buf, int j0) {
#pragma unroll
        for (int q = 0; q < 2; q++) {
            int r = wid * 16 + q * 8 + sr8;
            int c = sp8 ^ (r & 7);
            gl2lds(kbase + (long)(j0 + r) * 64 + c * 8, &lds_k[buf][(wid * 16 + q * 8) * 64]);
            gl2lds(vbase + (long)r * 1024 + j0 + c * 8, &lds_v[buf][(wid * 16 + q * 8) * 64]);
        }
    };

    stage(0, js * 512);
    __syncthreads();   // vmcnt(0) drained: buf0 ready
    int cur = 0;

#pragma unroll 1
    for (int jt = 0; jt < 8; jt++) {
        int j0 = js * 512 + jt * 64;
        if (jt < 7) stage(cur ^ 1, j0 + 64);   // in flight across the whole compute phase

        // S = q @ k^T  (16 rows x 64 cols per wave)
        f32x4 s_acc[4];
        __builtin_amdgcn_s_setprio(1);
#pragma unroll
        for (int nt = 0; nt < 4; nt++) {
            int r = nt * 16 + l15;
            u16x8 b0 = *(const u16x8*)&lds_k[cur][r * 64 + ((quad ^ (r & 7)) * 8)];
            u16x8 b1 = *(const u16x8*)&lds_k[cur][r * 64 + (((quad + 4) ^ (r & 7)) * 8)];
            f32x4 c = {};
            c = mfma16(aq[0], b0, c);
            c = mfma16(aq[1], b1, c);
            s_acc[nt] = c;
        }
        __builtin_amdgcn_s_setprio(0);

        // + rel+rpb from skew-space table (wave-uniform tile classification, inline)
#pragma unroll
        for (int nt = 0; nt < 4; nt++) {
            int jn0 = j0 + nt * 16;
            int jj = jn0 + l15;
            if (jn0 + 15 <= i0w) {
#pragma unroll
                for (int reg = 0; reg < 4; reg++) {
                    int ii = i0w + quad * 4 + reg;
                    s_acc[nt][reg] += bf2f(bbase[((long)ii << 10) + (ii - jj)]);
                }
            } else if (jn0 >= i0w + 17) {
#pragma unroll
                for (int reg = 0; reg < 4; reg++) {
                    int ii = i0w + quad * 4 + reg;
                    s_acc[nt][reg] += bf2f(bbase[((long)(ii + 1) << 10) + (ii + 1025 - jj)]);
                }
            } else {
#pragma unroll
                for (int reg = 0; reg < 4; reg++) {
                    int ii = i0w + quad * 4 + reg;
                    float a;
                    if (jj <= ii)          a = bf2f(bbase[((long)ii << 10) + (ii - jj)]);
                    else if (jj == ii + 1) a = rpb2046;
                    else                   a = bf2f(bbase[((long)(ii + 1) << 10) + (ii + 1025 - jj)]);
                    s_acc[nt][reg] += a;
                }
            }
        }

        // online softmax; T13 defer-max: skip rescale when max growth <= 8
        float mx[4];
#pragma unroll
        for (int reg = 0; reg < 4; reg++) {
            float m = fmaxf(fmaxf(s_acc[0][reg], s_acc[1][reg]), fmaxf(s_acc[2][reg], s_acc[3][reg]));
            for (int off = 1; off < 16; off <<= 1) m = fmaxf(m, __shfl_xor(m, off, 64));
            mx[reg] = m;
        }
        bool nogrow = (mx[0] <= m_r[0] + 8.f) && (mx[1] <= m_r[1] + 8.f) &&
                      (mx[2] <= m_r[2] + 8.f) && (mx[3] <= m_r[3] + 8.f);
        if (__all(nogrow)) {
#pragma unroll
            for (int reg = 0; reg < 4; reg++) {
                float rs = 0.f;
#pragma unroll
                for (int nt = 0; nt < 4; nt++) {
                    float p = __expf(s_acc[nt][reg] - m_r[reg]);
                    s_acc[nt][reg] = p;
                    rs += p;
                }
                for (int off = 1; off < 16; off <<= 1) rs += __shfl_xor(rs, off, 64);
                l_r[reg] += rs;
            }
        } else {
#pragma unroll
            for (int reg = 0; reg < 4; reg++) {
                float mnew = fmaxf(m_r[reg], mx[reg]);
                float alpha = __expf(m_r[reg] - mnew);
                float rs = 0.f;
#pragma unroll
                for (int nt = 0; nt < 4; nt++) {
                    float p = __expf(s_acc[nt][reg] - mnew);
                    s_acc[nt][reg] = p;
                    rs += p;
                }
                for (int off = 1; off < 16; off <<= 1) rs += __shfl_xor(rs, off, 64);
                l_r[reg] = l_r[reg] * alpha + rs;
                m_r[reg] = mnew;
#pragma unroll
                for (int dt = 0; dt < 4; dt++) o_acc[dt][reg] *= alpha;
            }
        }

        // P: C-layout -> LDS (chunk-swizzled) -> A-layout (same wave, no barrier)
#pragma unroll
        for (int nt = 0; nt < 4; nt++)
#pragma unroll
            for (int reg = 0; reg < 4; reg++) {
                int row = quad * 4 + reg;
                int pos = ((nt * 2 + (l15 >> 3)) ^ (row & 7)) * 8 + (l15 & 7);
                lds_p[wid][row * 64 + pos] = f2bf(s_acc[nt][reg]);
            }

        u16x8 pf0 = *(const u16x8*)&lds_p[wid][l15 * 64 + ((quad ^ (l15 & 7)) * 8)];
        u16x8 pf1 = *(const u16x8*)&lds_p[wid][l15 * 64 + (((quad + 4) ^ (l15 & 7)) * 8)];
        __builtin_amdgcn_s_setprio(1);
#pragma unroll
        for (int dt = 0; dt < 4; dt++) {
            int r = dt * 16 + l15;
            u16x8 v0 = *(const u16x8*)&lds_v[cur][r * 64 + ((quad ^ (r & 7)) * 8)];
            u16x8 v1 = *(const u16x8*)&lds_v[cur][r * 64 + (((quad + 4) ^ (r & 7)) * 8)];
            o_acc[dt] = mfma16(pf0, v0, o_acc[dt]);
            o_acc[dt] = mfma16(pf1, v1, o_acc[dt]);
        }
        __builtin_amdgcn_s_setprio(0);

        __syncthreads();   // all waves done with [cur]; drains staged loads for [cur^1]
        cur ^= 1;
    }

    int blk = (js * 32 + bh) * 16 + itile;
    float* PoB = Po + (long)blk * 4096;
#pragma unroll
    for (int dt = 0; dt < 4; dt++)
#pragma unroll
        for (int reg = 0; reg < 4; reg++) {
            int rr = wid * 16 + quad * 4 + reg;
            PoB[rr * 64 + dt * 16 + l15] = o_acc[dt][reg];
        }
    if (l15 == 0) {
#pragma unroll
        for (int reg = 0; reg < 4; reg++) {
            int rr = wid * 16 + quad * 4 + reg;
            Pm[blk * 64 + rr] = m_r[reg];
            Pl[blk * 64 + rr] = l_r[reg];
        }
    }
}

// ---------------- combine the 2 j-partials -> attn (bf16 [B,S,E]) -----------
__global__ __launch_bounds__(256) void combine_kernel(
    const float* __restrict__ Po, const float* __restrict__ Pm, const float* __restrict__ Pl,
    u16* __restrict__ attn)
{
    int itile = blockIdx.x, bh = blockIdx.y;
    int t = threadIdx.x;
    int c = t & 63, rg = t >> 6;
    int blk0 = bh * 16 + itile;
    int blk1 = (32 + bh) * 16 + itile;
    int b = bh >> 4, h = bh & 15;
    for (int rr = rg; rr < 64; rr += 4) {
        float m0 = Pm[blk0 * 64 + rr], m1 = Pm[blk1 * 64 + rr];
        float ms = fmaxf(m0, m1);
        float e0 = __expf(m0 - ms), e1 = __expf(m1 - ms);
        float l = Pl[blk0 * 64 + rr] * e0 + Pl[blk1 * 64 + rr] * e1;
        float o = Po[(long)blk0 * 4096 + rr * 64 + c] * e0
                + Po[(long)blk1 * 4096 + rr * 64 + c] * e1;
        int ii = itile * 64 + rr;
        attn[((long)(b * 1024 + ii)) * 1024 + h * 64 + c] = f2bf(o / l);
    }
}

// ---------------------------------------------------------------------------
extern "C" void kernel_launch(void* const* d_in, const int* in_sizes, int n_in,
                              void* d_out, int out_size, void* d_ws, size_t ws_size,
                              hipStream_t stream)
{
    const float* query = (const float*)d_in[0];
    const float* key_  = (const float*)d_in[1];
    const float* value = (const float*)d_in[2];
    const float* Wq = (const float*)d_in[3];
    const float* bq = (const float*)d_in[4];
    const float* Wk = (const float*)d_in[5];
    const float* bk = (const float*)d_in[6];
    const float* Wv = (const float*)d_in[7];
    const float* bv = (const float*)d_in[8];
    const float* Wo = (const float*)d_in[9];
    const float* bo = (const float*)d_in[10];
    const float* emb = (const float*)d_in[11];
    const float* rpb = (const float*)d_in[12];

    char* ws = (char*)d_ws;
    // live whole pipeline / early phase:
    u16* xq   = (u16*)(ws + 0);          // 4 MB   (dead after QKV gemm)
    u16* xk   = (u16*)(ws + 4194304);    // 4 MB   (dead after QKV gemm)
    u16* xv   = (u16*)(ws + 8388608);    // 4 MB   (dead after QKV gemm)
    u16* WqT  = (u16*)(ws + 12582912);   // 2 MB   (dead after QKV gemm)
    u16* WkT  = (u16*)(ws + 14680064);   // 2 MB   (dead after QKV gemm)
    u16* WvT  = (u16*)(ws + 16777216);   // 2 MB   (dead after QKV gemm)
    u16* embb = (u16*)(ws + 18874368);   // 512 KB (dead after gc)
    u16* WoT  = (u16*)(ws + 19922944);   // 2 MB   (live till final gemm)
    u16* qb   = (u16*)(ws + 22020096);   // 4 MB   (dead after flash)
    u16* kb   = (u16*)(ws + 26214400);   // 4 MB
    u16* vT   = (u16*)(ws + 30408704);   // 4 MB
    u16* Bskew= (u16*)(ws + 34603008);   // 64 MB -> ends 101711872
    // overlays (regions dead by the time these are written):
    float* Po = (float*)(ws + 0);          // 16 MB over xq/xk/xv/WqT/WkT
    float* Pm = (float*)(ws + 16777216);   // 256 KB over WvT
    float* Pl = (float*)(ws + 17039360);   // 256 KB over WvT
    u16* attn = (u16*)(ws + 22020096);     // 4 MB over qb

    cvt_kernel<<<6400, 256, 0, stream>>>(query, key_, value, emb, xq, xk, xv, embb);
    wt_kernel<<<dim3(16, 16, 4), dim3(64, 4), 0, stream>>>(Wq, Wk, Wv, Wo, WqT, WkT, WvT, WoT);
    gemm_kernel<2><<<dim3(8, 32, 3), 256, 0, stream>>>(xq, xk, xv, WqT, WkT, WvT,
                                                       bq, bk, bv, qb, kb, vT, nullptr, 0);
    gc_kernel<<<1024, 256, 0, stream>>>(qb, embb, rpb, Bskew);
    flash_kernel<<<dim3(16, 32, 2), 256, 0, stream>>>(qb, kb, vT, Bskew, rpb, Po, Pm, Pl);
    combine_kernel<<<dim3(16, 32), 256, 0, stream>>>(Po, Pm, Pl, attn);
    gemm_kernel<2><<<dim3(8, 32, 1), 256, 0, stream>>>(attn, nullptr, nullptr, WoT, nullptr, nullptr,
                                                       bo, nullptr, nullptr,
                                                       nullptr, nullptr, nullptr, (float*)d_out, 3);
}

// Round 12
// 237.506 us; speedup vs baseline: 1.2174x; 1.2174x over previous
//
#include <hip/hip_runtime.h>

typedef unsigned short u16;
typedef __bf16 bf16_t;
typedef bf16_t bf16x8 __attribute__((ext_vector_type(8)));
typedef u16 u16x8 __attribute__((ext_vector_type(8)));
typedef float f32x4 __attribute__((ext_vector_type(4)));

#define DEVI __device__ __forceinline__

// B=2, S=1024, E=1024, H=16, DH=64, MAXLEN=2048, table=4095

DEVI u16 f2bf(float f) {
    unsigned u = __builtin_bit_cast(unsigned, f);
    u = (u + 0x7FFFu + ((u >> 16) & 1u)) >> 16;
    return (u16)u;
}
DEVI float bf2f(u16 b) {
    unsigned u = ((unsigned)b) << 16;
    return __builtin_bit_cast(float, u);
}
DEVI f32x4 mfma16(u16x8 a, u16x8 b, f32x4 c) {
    return __builtin_amdgcn_mfma_f32_16x16x32_bf16(
        __builtin_bit_cast(bf16x8, a), __builtin_bit_cast(bf16x8, b), c, 0, 0, 0);
}
// async global->LDS, 16B per lane; LDS dest = base + lane*16 (wave-uniform base)
DEVI void gl2lds(const u16* g, u16* l) {
    __builtin_amdgcn_global_load_lds(
        (__attribute__((address_space(1))) void*)g,
        (__attribute__((address_space(3))) void*)l, 16, 0, 0);
}

// ---------------- convert fp32 -> bf16 (query,key,value,emb) ----------------
__global__ __launch_bounds__(256) void cvt_kernel(
    const float* __restrict__ q, const float* __restrict__ k, const float* __restrict__ v,
    const float* __restrict__ emb,
    u16* __restrict__ xq, u16* __restrict__ xk, u16* __restrict__ xv, u16* __restrict__ embb)
{
    const long NQ = 2097152;   // 2*1024*1024
    const long NE = 262080;    // 4095*64
    long i4 = ((long)blockIdx.x * 256 + threadIdx.x) * 4;
    if (i4 < 3 * NQ) {
        int which = (int)(i4 >> 21);
        long off = i4 & (NQ - 1);
        const float* src = which == 0 ? q : (which == 1 ? k : v);
        u16* dst = which == 0 ? xq : (which == 1 ? xk : xv);
        float4 f = *(const float4*)(src + off);
        ushort4 o; o.x = f2bf(f.x); o.y = f2bf(f.y); o.z = f2bf(f.z); o.w = f2bf(f.w);
        *(ushort4*)(dst + off) = o;
    } else {
        long off = i4 - 3 * NQ;
        if (off < NE) {
            float4 f = *(const float4*)(emb + off);
            ushort4 o; o.x = f2bf(f.x); o.y = f2bf(f.y); o.z = f2bf(f.z); o.w = f2bf(f.w);
            *(ushort4*)(embb + off) = o;
        }
    }
}

// ---------------- W [K][N] fp32 -> WT [N][K] bf16 (tiled transpose) ---------
__global__ __launch_bounds__(256) void wt_kernel(
    const float* __restrict__ w0, const float* __restrict__ w1,
    const float* __restrict__ w2, const float* __restrict__ w3,
    u16* __restrict__ t0, u16* __restrict__ t1, u16* __restrict__ t2, u16* __restrict__ t3)
{
    int z = blockIdx.z;
    const float* W = z == 0 ? w0 : (z == 1 ? w1 : (z == 2 ? w2 : w3));
    u16* T = z == 0 ? t0 : (z == 1 ? t1 : (z == 2 ? t2 : t3));
    __shared__ float tile[64][65];
    int k0 = blockIdx.y * 64, n0 = blockIdx.x * 64;
    int tx = threadIdx.x, ty = threadIdx.y;   // (64,4)
    for (int r = ty; r < 64; r += 4)
        tile[r][tx] = W[(long)(k0 + r) * 1024 + n0 + tx];
    __syncthreads();
    for (int r = ty; r < 64; r += 4)
        T[(long)(n0 + r) * 1024 + k0 + tx] = f2bf(tile[tx][r]);
}

// ---------------- bf16 MFMA GEMM, dbuf global_load_lds, BK=64, XCD swizzle --
// C tile (MT*32) x 128; A[M][1024], WT[N][1024] (both row-major K)
// Per buf: two 32-k half-tiles [half][row][32 u16], chunk (8 u16) swizzle
// pos p = c ^ ((row>>1)&3) within each half.  16 K-iterations (BK=64) ->
// half the barriers of the BK=32 version; same total load/MFMA counts.
// Grid (8, GY, z), GY % 4 == 0.  XCD swizzle: per-XCD 4 x-tiles x GY/4 y-tiles.
// mode 0: q-proj ((acc+b)*0.125 -> qb); 1: k-proj -> kb; 2: v-proj -> vT;
// mode 3: out-proj -> fp32 [M][N]
template<int MT>
__global__ __launch_bounds__(256) void gemm_kernel(
    const u16* __restrict__ A0, const u16* __restrict__ A1, const u16* __restrict__ A2,
    const u16* __restrict__ W0, const u16* __restrict__ W1, const u16* __restrict__ W2,
    const float* __restrict__ bias0, const float* __restrict__ bias1, const float* __restrict__ bias2,
    u16* __restrict__ o0, u16* __restrict__ o1, u16* __restrict__ o2,
    float* __restrict__ ofp, int mode_base)
{
    int z = blockIdx.z;
    int mode = mode_base + z;
    const u16* A = z == 0 ? A0 : (z == 1 ? A1 : A2);
    const u16* W = z == 0 ? W0 : (z == 1 ? W1 : W2);
    const float* bias = z == 0 ? bias0 : (z == 1 ? bias1 : bias2);
    u16* ob = z == 0 ? o0 : (z == 1 ? o1 : o2);

    constexpr int MROWS = MT * 32;
    __shared__ u16 la[2 * 2 * MROWS * 32];   // [buf][half][row][32]
    __shared__ u16 lw[2 * 2 * 128 * 32];

    // XCD-aware bijective swizzle for (8, GY) grids
    int lin = blockIdx.x + (blockIdx.y << 3);
    int xcd = lin & 7, idx = lin >> 3;
    int gy4 = gridDim.y >> 2;
    int xt = (xcd & 1) * 4 + (idx & 3);
    int yt = (xcd >> 1) * gy4 + (idx >> 2);
    int m0 = yt * MROWS, n0 = xt * 128;

    int t = threadIdx.x, lane = t & 63, wid = t >> 6;
    int l15 = lane & 15, quad = lane >> 4;
    int wm = (wid >> 1) * (MT * 16), wn = (wid & 1) * 64;
    int sr = lane >> 2, sp = lane & 3;   // staging: 16 rows x 4 chunks per instr

    f32x4 acc[MT][4] = {};

    auto stage_half = [&](int buf, int half, int k0) {
#pragma unroll
        for (int q = 0; q < MT / 2; q++) {
            int r = wid * (MT * 8) + q * 16 + sr;
            int c = sp ^ ((r >> 1) & 3);
            gl2lds(A + (long)(m0 + r) * 1024 + k0 + c * 8,
                   la + (buf * 2 + half) * (MROWS * 32) + (wid * (MT * 8) + q * 16) * 32);
        }
#pragma unroll
        for (int q = 0; q < 2; q++) {
            int r = wid * 32 + q * 16 + sr;
            int c = sp ^ ((r >> 1) & 3);
            gl2lds(W + (long)(n0 + r) * 1024 + k0 + c * 8,
                   lw + (buf * 2 + half) * (128 * 32) + (wid * 32 + q * 16) * 32);
        }
    };
    auto stage = [&](int buf, int k0) {
        stage_half(buf, 0, k0);
        stage_half(buf, 1, k0 + 32);
    };

    stage(0, 0);
    __syncthreads();
    int cur = 0;
#pragma unroll 1
    for (int k0 = 0; k0 < 1024; k0 += 64) {
        if (k0 < 960) stage(cur ^ 1, k0 + 64);   // prefetch next K-step (in flight during compute)
#pragma unroll
        for (int h = 0; h < 2; h++) {
            const u16* lab = la + (cur * 2 + h) * (MROWS * 32);
            const u16* lwb = lw + (cur * 2 + h) * (128 * 32);
            u16x8 af[MT], bfr[4];
#pragma unroll
            for (int mt = 0; mt < MT; mt++) {
                int r = wm + mt * 16 + l15;
                af[mt] = *(const u16x8*)&lab[r * 32 + ((quad ^ ((r >> 1) & 3)) * 8)];
            }
#pragma unroll
            for (int nt = 0; nt < 4; nt++) {
                int r = wn + nt * 16 + l15;
                bfr[nt] = *(const u16x8*)&lwb[r * 32 + ((quad ^ ((r >> 1) & 3)) * 8)];
            }
#pragma unroll
            for (int mt = 0; mt < MT; mt++)
#pragma unroll
                for (int nt = 0; nt < 4; nt++)
                    acc[mt][nt] = mfma16(af[mt], bfr[nt], acc[mt][nt]);
        }
        __syncthreads();   // drains vmcnt (next buf staged) + lgkm; one barrier per 64-k
        cur ^= 1;
    }

#pragma unroll
    for (int mt = 0; mt < MT; mt++)
#pragma unroll
        for (int nt = 0; nt < 4; nt++)
#pragma unroll
            for (int reg = 0; reg < 4; reg++) {
                int gm = m0 + wm + mt * 16 + quad * 4 + reg;   // C row = quad*4+reg
                int gn = n0 + wn + nt * 16 + l15;              // C col = lane&15
                float val = acc[mt][nt][reg] + bias[gn];
                if (mode == 0) {
                    val *= 0.125f;   // 1/sqrt(DH)
                    long o = ((long)((gm >> 10) * 16 + (gn >> 6)) << 16) + ((gm & 1023) << 6) + (gn & 63);
                    ob[o] = f2bf(val);
                } else if (mode == 1) {
                    long o = ((long)((gm >> 10) * 16 + (gn >> 6)) << 16) + ((gm & 1023) << 6) + (gn & 63);
                    ob[o] = f2bf(val);
                } else if (mode == 2) {
                    long o = ((long)((gm >> 10) * 16 + (gn >> 6)) << 16) + ((long)(gn & 63) << 10) + (gm & 1023);
                    ob[o] = f2bf(val);
                } else {
                    ofp[(long)gm * 1024 + gn] = val;
                }
            }
}

// ---------------- Gc skewed GEMM -> SKEW-SPACE table Bskew ------------------
// Bskew[u][cc] = q[u] . emb[1024 + i_u + cc] + (cc<=i_u ? rpb[cc+2047] : rpb[cc+1022])
// (i_u = u & 1023, cc in [0,1023]).  Consumed by flash:
//   j <= i   : rel+rpb = Bskew[i][i-j]
//   j == i+1 : rel+rpb = rpb[2046]
//   j >= i+2 : rel+rpb = Bskew[i+1][i+1025-j]
__global__ __launch_bounds__(256) void gc_kernel(
    const u16* __restrict__ qb, const u16* __restrict__ embb,
    const float* __restrict__ rpb, u16* __restrict__ Bskew)
{
    int u0 = blockIdx.x * 32;
    int i0 = u0 & 1023;
    int t = threadIdx.x, lane = t & 63, wid = t >> 6;
    int l15 = lane & 15, quad = lane >> 4;

    __shared__ float lds_rpb[2048];   // [cc]=rpb[cc+2047], [1024+cc]=rpb[cc+1022]
    for (int j = t; j < 1024; j += 256) {
        lds_rpb[j] = rpb[j + 2047];
        lds_rpb[1024 + j] = rpb[j + 1022];
    }
    __syncthreads();

    // A fragments: rows u0 .. u0+31 (2 row-groups of 16)
    u16x8 aq[2][2];
#pragma unroll
    for (int rg = 0; rg < 2; rg++) {
        long qoff = (long)(u0 + rg * 16 + l15) * 64 + quad * 8;
        aq[rg][0] = *(const u16x8*)&qb[qoff];
        aq[rg][1] = *(const u16x8*)&qb[qoff + 32];
    }

    // prefetch first emb tile for this wave
    u16x8 nb0, nb1;
    {
        long ebase = (long)(1024 + i0 + wid * 16 + l15) * 64 + quad * 8;
        nb0 = *(const u16x8*)&embb[ebase];
        nb1 = *(const u16x8*)&embb[ebase + 32];
    }

    // w-tiles 0..65 cover w in [0,1056); max needed w = 1023+31 = 1054
    for (int tt = wid; tt < 66; tt += 4) {
        u16x8 b0 = nb0, b1 = nb1;
        if (tt + 4 < 66) {
            long ebase = (long)(1024 + i0 + (tt + 4) * 16 + l15) * 64 + quad * 8;
            nb0 = *(const u16x8*)&embb[ebase];
            nb1 = *(const u16x8*)&embb[ebase + 32];
        }
        int w0 = tt * 16;
#pragma unroll
        for (int rg = 0; rg < 2; rg++) {
            f32x4 c = {};
            c = mfma16(aq[rg][0], b0, c);
            c = mfma16(aq[rg][1], b1, c);
#pragma unroll
            for (int reg = 0; reg < 4; reg++) {
                int row = rg * 16 + quad * 4 + reg;
                int cc = w0 + l15 - row;
                if ((unsigned)cc <= 1023u) {
                    int i = i0 + row;
                    float rb = lds_rpb[cc + ((cc <= i) ? 0 : 1024)];
                    Bskew[((long)(u0 + row) << 10) + cc] = f2bf(c[reg] + rb);
                }
            }
        }
    }
}

// ---------------- flash attention (j-split x2, dbuf K/V @ 40960B LDS) -------
// r10-verified structure (47.4us, 0 bank conflicts, clean traffic).
// Double-buffered K/V (32KB) + swizzled un-padded lds_p (8KB) = exactly 40960B.
// Tiles [64 rows][64 u16], chunk (8 u16) swizzle: pos p = c ^ (row&7);
// lds_p element (row,c) stored at row*64 + ((c>>3)^(row&7))*8 + (c&7).
__global__ __launch_bounds__(256, 4) void flash_kernel(
    const u16* __restrict__ qb, const u16* __restrict__ kb, const u16* __restrict__ vT,
    const u16* __restrict__ Bskew, const float* __restrict__ rpb,
    float* __restrict__ Po, float* __restrict__ Pm, float* __restrict__ Pl)
{
    int itile = blockIdx.x;        // 0..15
    int bh = blockIdx.y;           // 0..31
    int js = blockIdx.z;           // 0..1
    int t = threadIdx.x, lane = t & 63, wid = t >> 6;
    int l15 = lane & 15, quad = lane >> 4;
    int i0w = itile * 64 + wid * 16;

    __shared__ u16 lds_k[2][64 * 64];  // [j][d]
    __shared__ u16 lds_v[2][64 * 64];  // [d][j]
    __shared__ u16 lds_p[4][1024];     // per-wave P, chunk-swizzled, no pad

    int sr8 = lane >> 3, sp8 = lane & 7;   // staging: 8 rows x 8 chunks per instr

    float rpb2046 = rpb[2046];

    u16x8 aq[2];
    {
        long qoff = ((long)(bh * 1024) + i0w + l15) * 64 + quad * 8;
        aq[0] = *(const u16x8*)&qb[qoff];
        aq[1] = *(const u16x8*)&qb[qoff + 32];
    }
    float m_r[4], l_r[4];
    f32x4 o_acc[4] = {};
#pragma unroll
    for (int r = 0; r < 4; r++) { m_r[r] = -1e30f; l_r[r] = 0.f; }

    const u16* kbase = kb + (long)bh * 65536;
    const u16* vbase = vT + (long)bh * 65536;
    const u16* bbase = Bskew + ((long)bh << 20);

    auto stage = [&](int buf, int j0) {
#pragma unroll
        for (int q = 0; q < 2; q++) {
            int r = wid * 16 + q * 8 + sr8;
            int c = sp8 ^ (r & 7);
            gl2lds(kbase + (long)(j0 + r) * 64 + c * 8, &lds_k[buf][(wid * 16 + q * 8) * 64]);
            gl2lds(vbase + (long)r * 1024 + j0 + c * 8, &lds_v[buf][(wid * 16 + q * 8) * 64]);
        }
    };

    stage(0, js * 512);
    __syncthreads();   // vmcnt(0) drained: buf0 ready
    int cur = 0;

#pragma unroll 1
    for (int jt = 0; jt < 8; jt++) {
        int j0 = js * 512 + jt * 64;
        if (jt < 7) stage(cur ^ 1, j0 + 64);   // in flight across the whole compute phase

        // S = q @ k^T  (16 rows x 64 cols per wave)
        f32x4 s_acc[4];
#pragma unroll
        for (int nt = 0; nt < 4; nt++) {
            int r = nt * 16 + l15;
            u16x8 b0 = *(const u16x8*)&lds_k[cur][r * 64 + ((quad ^ (r & 7)) * 8)];
            u16x8 b1 = *(const u16x8*)&lds_k[cur][r * 64 + (((quad + 4) ^ (r & 7)) * 8)];
            f32x4 c = {};
            c = mfma16(aq[0], b0, c);
            c = mfma16(aq[1], b1, c);
            s_acc[nt] = c;
        }

        // + rel+rpb from skew-space table (wave-uniform tile classification, inline)
#pragma unroll
        for (int nt = 0; nt < 4; nt++) {
            int jn0 = j0 + nt * 16;
            int jj = jn0 + l15;
            if (jn0 + 15 <= i0w) {
#pragma unroll
                for (int reg = 0; reg < 4; reg++) {
                    int ii = i0w + quad * 4 + reg;
                    s_acc[nt][reg] += bf2f(bbase[((long)ii << 10) + (ii - jj)]);
                }
            } else if (jn0 >= i0w + 17) {
#pragma unroll
                for (int reg = 0; reg < 4; reg++) {
                    int ii = i0w + quad * 4 + reg;
                    s_acc[nt][reg] += bf2f(bbase[((long)(ii + 1) << 10) + (ii + 1025 - jj)]);
                }
            } else {
#pragma unroll
                for (int reg = 0; reg < 4; reg++) {
                    int ii = i0w + quad * 4 + reg;
                    float a;
                    if (jj <= ii)          a = bf2f(bbase[((long)ii << 10) + (ii - jj)]);
                    else if (jj == ii + 1) a = rpb2046;
                    else                   a = bf2f(bbase[((long)(ii + 1) << 10) + (ii + 1025 - jj)]);
                    s_acc[nt][reg] += a;
                }
            }
        }

        // online softmax (rows at quad*4+reg, 16 lanes per row-group)
#pragma unroll
        for (int reg = 0; reg < 4; reg++) {
            float mx = fmaxf(fmaxf(s_acc[0][reg], s_acc[1][reg]), fmaxf(s_acc[2][reg], s_acc[3][reg]));
            for (int off = 1; off < 16; off <<= 1) mx = fmaxf(mx, __shfl_xor(mx, off, 64));
            float mnew = fmaxf(m_r[reg], mx);
            float alpha = __expf(m_r[reg] - mnew);
            float rs = 0.f;
#pragma unroll
            for (int nt = 0; nt < 4; nt++) {
                float p = __expf(s_acc[nt][reg] - mnew);
                s_acc[nt][reg] = p;
                rs += p;
            }
            for (int off = 1; off < 16; off <<= 1) rs += __shfl_xor(rs, off, 64);
            l_r[reg] = l_r[reg] * alpha + rs;
            m_r[reg] = mnew;
#pragma unroll
            for (int dt = 0; dt < 4; dt++) o_acc[dt][reg] *= alpha;
        }

        // P: C-layout -> LDS (chunk-swizzled) -> A-layout (same wave, no barrier)
#pragma unroll
        for (int nt = 0; nt < 4; nt++)
#pragma unroll
            for (int reg = 0; reg < 4; reg++) {
                int row = quad * 4 + reg;
                int pos = ((nt * 2 + (l15 >> 3)) ^ (row & 7)) * 8 + (l15 & 7);
                lds_p[wid][row * 64 + pos] = f2bf(s_acc[nt][reg]);
            }

        u16x8 pf0 = *(const u16x8*)&lds_p[wid][l15 * 64 + ((quad ^ (l15 & 7)) * 8)];
        u16x8 pf1 = *(const u16x8*)&lds_p[wid][l15 * 64 + (((quad + 4) ^ (l15 & 7)) * 8)];
#pragma unroll
        for (int dt = 0; dt < 4; dt++) {
            int r = dt * 16 + l15;
            u16x8 v0 = *(const u16x8*)&lds_v[cur][r * 64 + ((quad ^ (r & 7)) * 8)];
            u16x8 v1 = *(const u16x8*)&lds_v[cur][r * 64 + (((quad + 4) ^ (r & 7)) * 8)];
            o_acc[dt] = mfma16(pf0, v0, o_acc[dt]);
            o_acc[dt] = mfma16(pf1, v1, o_acc[dt]);
        }

        __syncthreads();   // all waves done with [cur]; drains staged loads for [cur^1]
        cur ^= 1;
    }

    int blk = (js * 32 + bh) * 16 + itile;
    float* PoB = Po + (long)blk * 4096;
#pragma unroll
    for (int dt = 0; dt < 4; dt++)
#pragma unroll
        for (int reg = 0; reg < 4; reg++) {
            int rr = wid * 16 + quad * 4 + reg;
            PoB[rr * 64 + dt * 16 + l15] = o_acc[dt][reg];
        }
    if (l15 == 0) {
#pragma unroll
        for (int reg = 0; reg < 4; reg++) {
            int rr = wid * 16 + quad * 4 + reg;
            Pm[blk * 64 + rr] = m_r[reg];
            Pl[blk * 64 + rr] = l_r[reg];
        }
    }
}

// ---------------- combine the 2 j-partials -> attn (bf16 [B,S,E]) -----------
__global__ __launch_bounds__(256) void combine_kernel(
    const float* __restrict__ Po, const float* __restrict__ Pm, const float* __restrict__ Pl,
    u16* __restrict__ attn)
{
    int itile = blockIdx.x, bh = blockIdx.y;
    int t = threadIdx.x;
    int c = t & 63, rg = t >> 6;
    int blk0 = bh * 16 + itile;
    int blk1 = (32 + bh) * 16 + itile;
    int b = bh >> 4, h = bh & 15;
    for (int rr = rg; rr < 64; rr += 4) {
        float m0 = Pm[blk0 * 64 + rr], m1 = Pm[blk1 * 64 + rr];
        float ms = fmaxf(m0, m1);
        float e0 = __expf(m0 - ms), e1 = __expf(m1 - ms);
        float l = Pl[blk0 * 64 + rr] * e0 + Pl[blk1 * 64 + rr] * e1;
        float o = Po[(long)blk0 * 4096 + rr * 64 + c] * e0
                + Po[(long)blk1 * 4096 + rr * 64 + c] * e1;
        int ii = itile * 64 + rr;
        attn[((long)(b * 1024 + ii)) * 1024 + h * 64 + c] = f2bf(o / l);
    }
}

// ---------------------------------------------------------------------------
extern "C" void kernel_launch(void* const* d_in, const int* in_sizes, int n_in,
                              void* d_out, int out_size, void* d_ws, size_t ws_size,
                              hipStream_t stream)
{
    const float* query = (const float*)d_in[0];
    const float* key_  = (const float*)d_in[1];
    const float* value = (const float*)d_in[2];
    const float* Wq = (const float*)d_in[3];
    const float* bq = (const float*)d_in[4];
    const float* Wk = (const float*)d_in[5];
    const float* bk = (const float*)d_in[6];
    const float* Wv = (const float*)d_in[7];
    const float* bv = (const float*)d_in[8];
    const float* Wo = (const float*)d_in[9];
    const float* bo = (const float*)d_in[10];
    const float* emb = (const float*)d_in[11];
    const float* rpb = (const float*)d_in[12];

    char* ws = (char*)d_ws;
    // live whole pipeline / early phase:
    u16* xq   = (u16*)(ws + 0);          // 4 MB   (dead after QKV gemm)
    u16* xk   = (u16*)(ws + 4194304);    // 4 MB   (dead after QKV gemm)
    u16* xv   = (u16*)(ws + 8388608);    // 4 MB   (dead after QKV gemm)
    u16* WqT  = (u16*)(ws + 12582912);   // 2 MB   (dead after QKV gemm)
    u16* WkT  = (u16*)(ws + 14680064);   // 2 MB   (dead after QKV gemm)
    u16* WvT  = (u16*)(ws + 16777216);   // 2 MB   (dead after QKV gemm)
    u16* embb = (u16*)(ws + 18874368);   // 512 KB (dead after gc)
    u16* WoT  = (u16*)(ws + 19922944);   // 2 MB   (live till final gemm)
    u16* qb   = (u16*)(ws + 22020096);   // 4 MB   (dead after flash)
    u16* kb   = (u16*)(ws + 26214400);   // 4 MB
    u16* vT   = (u16*)(ws + 30408704);   // 4 MB
    u16* Bskew= (u16*)(ws + 34603008);   // 64 MB -> ends 101711872
    // overlays (regions dead by the time these are written):
    float* Po = (float*)(ws + 0);          // 16 MB over xq/xk/xv/WqT/WkT
    float* Pm = (float*)(ws + 16777216);   // 256 KB over WvT
    float* Pl = (float*)(ws + 17039360);   // 256 KB over WvT
    u16* attn = (u16*)(ws + 22020096);     // 4 MB over qb

    cvt_kernel<<<6400, 256, 0, stream>>>(query, key_, value, emb, xq, xk, xv, embb);
    wt_kernel<<<dim3(16, 16, 4), dim3(64, 4), 0, stream>>>(Wq, Wk, Wv, Wo, WqT, WkT, WvT, WoT);
    gemm_kernel<2><<<dim3(8, 32, 3), 256, 0, stream>>>(xq, xk, xv, WqT, WkT, WvT,
                                                       bq, bk, bv, qb, kb, vT, nullptr, 0);
    gc_kernel<<<1024, 256, 0, stream>>>(qb, embb, rpb, Bskew);
    flash_kernel<<<dim3(16, 32, 2), 256, 0, stream>>>(qb, kb, vT, Bskew, rpb, Po, Pm, Pl);
    combine_kernel<<<dim3(16, 32), 256, 0, stream>>>(Po, Pm, Pl, attn);
    gemm_kernel<2><<<dim3(8, 32, 1), 256, 0, stream>>>(attn, nullptr, nullptr, WoT, nullptr, nullptr,
                                                       bo, nullptr, nullptr,
                                                       nullptr, nullptr, nullptr, (float*)d_out, 3);
}

// Round 14
// 230.354 us; speedup vs baseline: 1.2552x; 1.0311x over previous
//
#include <hip/hip_runtime.h>

typedef unsigned short u16;
typedef __bf16 bf16_t;
typedef bf16_t bf16x8 __attribute__((ext_vector_type(8)));
typedef u16 u16x8 __attribute__((ext_vector_type(8)));
typedef float f32x4 __attribute__((ext_vector_type(4)));

#define DEVI __device__ __forceinline__

// B=2, S=1024, E=1024, H=16, DH=64, MAXLEN=2048, table=4095

DEVI u16 f2bf(float f) {
    unsigned u = __builtin_bit_cast(unsigned, f);
    u = (u + 0x7FFFu + ((u >> 16) & 1u)) >> 16;
    return (u16)u;
}
DEVI float bf2f(u16 b) {
    unsigned u = ((unsigned)b) << 16;
    return __builtin_bit_cast(float, u);
}
DEVI f32x4 mfma16(u16x8 a, u16x8 b, f32x4 c) {
    return __builtin_amdgcn_mfma_f32_16x16x32_bf16(
        __builtin_bit_cast(bf16x8, a), __builtin_bit_cast(bf16x8, b), c, 0, 0, 0);
}
// async global->LDS, 16B per lane; LDS dest = base + lane*16 (wave-uniform base)
DEVI void gl2lds(const u16* g, u16* l) {
    __builtin_amdgcn_global_load_lds(
        (__attribute__((address_space(1))) void*)g,
        (__attribute__((address_space(3))) void*)l, 16, 0, 0);
}

// ------- fused: convert fp32->bf16 (q,k,v,emb) + W transposes (one launch) --
// blocks [0,6400): cvt;  blocks [6400,7424): wt (1024 blocks = 16x16x4)
__global__ __launch_bounds__(256) void cvtwt_kernel(
    const float* __restrict__ q, const float* __restrict__ k, const float* __restrict__ v,
    const float* __restrict__ emb,
    const float* __restrict__ w0, const float* __restrict__ w1,
    const float* __restrict__ w2, const float* __restrict__ w3,
    u16* __restrict__ xq, u16* __restrict__ xk, u16* __restrict__ xv, u16* __restrict__ embb,
    u16* __restrict__ t0, u16* __restrict__ t1, u16* __restrict__ t2, u16* __restrict__ t3)
{
    __shared__ float tile[64][65];
    int t = threadIdx.x;
    if (blockIdx.x < 6400) {
        const long NQ = 2097152;   // 2*1024*1024
        const long NE = 262080;    // 4095*64
        long i4 = ((long)blockIdx.x * 256 + t) * 4;
        if (i4 < 3 * NQ) {
            int which = (int)(i4 >> 21);
            long off = i4 & (NQ - 1);
            const float* src = which == 0 ? q : (which == 1 ? k : v);
            u16* dst = which == 0 ? xq : (which == 1 ? xk : xv);
            float4 f = *(const float4*)(src + off);
            ushort4 o; o.x = f2bf(f.x); o.y = f2bf(f.y); o.z = f2bf(f.z); o.w = f2bf(f.w);
            *(ushort4*)(dst + off) = o;
        } else {
            long off = i4 - 3 * NQ;
            if (off < NE) {
                float4 f = *(const float4*)(emb + off);
                ushort4 o; o.x = f2bf(f.x); o.y = f2bf(f.y); o.z = f2bf(f.z); o.w = f2bf(f.w);
                *(ushort4*)(embb + off) = o;
            }
        }
    } else {
        int wb = blockIdx.x - 6400;        // 0..1023
        int z = wb >> 8;                   // 0..3
        int by = (wb >> 4) & 15, bx = wb & 15;
        const float* W = z == 0 ? w0 : (z == 1 ? w1 : (z == 2 ? w2 : w3));
        u16* T = z == 0 ? t0 : (z == 1 ? t1 : (z == 2 ? t2 : t3));
        int k0 = by * 64, n0 = bx * 64;
        int tx = t & 63, ty = t >> 6;      // (64,4)
        for (int r = ty; r < 64; r += 4)
            tile[r][tx] = W[(long)(k0 + r) * 1024 + n0 + tx];
        __syncthreads();
        for (int r = ty; r < 64; r += 4)
            T[(long)(n0 + r) * 1024 + k0 + tx] = f2bf(tile[tx][r]);
    }
}

// ---------------- bf16 MFMA GEMM, dbuf global_load_lds, BK=64, XCD swizzle --
// C tile (MT*32) x 128; A[M][1024], WT[N][1024] (both row-major K)
// Per buf: two 32-k half-tiles [half][row][32 u16], chunk (8 u16) swizzle
// pos p = c ^ ((row>>1)&3) within each half.  16 K-iterations (BK=64).
// Grid (8, GY, z), GY % 4 == 0.  XCD swizzle: per-XCD 4 x-tiles x GY/4 y-tiles.
// mode 0: q-proj ((acc+b)*0.125 -> qb); 1: k-proj -> kb; 2: v-proj -> vT;
// mode 3: out-proj -> fp32 [M][N]
template<int MT>
__global__ __launch_bounds__(256) void gemm_kernel(
    const u16* __restrict__ A0, const u16* __restrict__ A1, const u16* __restrict__ A2,
    const u16* __restrict__ W0, const u16* __restrict__ W1, const u16* __restrict__ W2,
    const float* __restrict__ bias0, const float* __restrict__ bias1, const float* __restrict__ bias2,
    u16* __restrict__ o0, u16* __restrict__ o1, u16* __restrict__ o2,
    float* __restrict__ ofp, int mode_base)
{
    int z = blockIdx.z;
    int mode = mode_base + z;
    const u16* A = z == 0 ? A0 : (z == 1 ? A1 : A2);
    const u16* W = z == 0 ? W0 : (z == 1 ? W1 : W2);
    const float* bias = z == 0 ? bias0 : (z == 1 ? bias1 : bias2);
    u16* ob = z == 0 ? o0 : (z == 1 ? o1 : o2);

    constexpr int MROWS = MT * 32;
    __shared__ u16 la[2 * 2 * MROWS * 32];   // [buf][half][row][32]
    __shared__ u16 lw[2 * 2 * 128 * 32];

    // XCD-aware bijective swizzle for (8, GY) grids
    int lin = blockIdx.x + (blockIdx.y << 3);
    int xcd = lin & 7, idx = lin >> 3;
    int gy4 = gridDim.y >> 2;
    int xt = (xcd & 1) * 4 + (idx & 3);
    int yt = (xcd >> 1) * gy4 + (idx >> 2);
    int m0 = yt * MROWS, n0 = xt * 128;

    int t = threadIdx.x, lane = t & 63, wid = t >> 6;
    int l15 = lane & 15, quad = lane >> 4;
    int wm = (wid >> 1) * (MT * 16), wn = (wid & 1) * 64;
    int sr = lane >> 2, sp = lane & 3;   // staging: 16 rows x 4 chunks per instr

    f32x4 acc[MT][4] = {};

    auto stage_half = [&](int buf, int half, int k0) {
        if constexpr (MT == 1) {
            // A half-tile is 32 rows: waves 0,1 stage 16 rows each
            if (wid < 2) {
                int r = wid * 16 + sr;
                int c = sp ^ ((r >> 1) & 3);
                gl2lds(A + (long)(m0 + r) * 1024 + k0 + c * 8,
                       la + (buf * 2 + half) * (MROWS * 32) + (wid * 16) * 32);
            }
        } else {
#pragma unroll
            for (int q = 0; q < MT / 2; q++) {
                int r = wid * (MT * 8) + q * 16 + sr;
                int c = sp ^ ((r >> 1) & 3);
                gl2lds(A + (long)(m0 + r) * 1024 + k0 + c * 8,
                       la + (buf * 2 + half) * (MROWS * 32) + (wid * (MT * 8) + q * 16) * 32);
            }
        }
#pragma unroll
        for (int q = 0; q < 2; q++) {
            int r = wid * 32 + q * 16 + sr;
            int c = sp ^ ((r >> 1) & 3);
            gl2lds(W + (long)(n0 + r) * 1024 + k0 + c * 8,
                   lw + (buf * 2 + half) * (128 * 32) + (wid * 32 + q * 16) * 32);
        }
    };
    auto stage = [&](int buf, int k0) {
        stage_half(buf, 0, k0);
        stage_half(buf, 1, k0 + 32);
    };

    stage(0, 0);
    __syncthreads();
    int cur = 0;
#pragma unroll 1
    for (int k0 = 0; k0 < 1024; k0 += 64) {
        if (k0 < 960) stage(cur ^ 1, k0 + 64);   // prefetch next K-step (in flight during compute)
#pragma unroll
        for (int h = 0; h < 2; h++) {
            const u16* lab = la + (cur * 2 + h) * (MROWS * 32);
            const u16* lwb = lw + (cur * 2 + h) * (128 * 32);
            u16x8 af[MT], bfr[4];
#pragma unroll
            for (int mt = 0; mt < MT; mt++) {
                int r = wm + mt * 16 + l15;
                af[mt] = *(const u16x8*)&lab[r * 32 + ((quad ^ ((r >> 1) & 3)) * 8)];
            }
#pragma unroll
            for (int nt = 0; nt < 4; nt++) {
                int r = wn + nt * 16 + l15;
                bfr[nt] = *(const u16x8*)&lwb[r * 32 + ((quad ^ ((r >> 1) & 3)) * 8)];
            }
#pragma unroll
            for (int mt = 0; mt < MT; mt++)
#pragma unroll
                for (int nt = 0; nt < 4; nt++)
                    acc[mt][nt] = mfma16(af[mt], bfr[nt], acc[mt][nt]);
        }
        __syncthreads();   // drains vmcnt (next buf staged) + lgkm; one barrier per 64-k
        cur ^= 1;
    }

#pragma unroll
    for (int mt = 0; mt < MT; mt++)
#pragma unroll
        for (int nt = 0; nt < 4; nt++)
#pragma unroll
            for (int reg = 0; reg < 4; reg++) {
                int gm = m0 + wm + mt * 16 + quad * 4 + reg;   // C row = quad*4+reg
                int gn = n0 + wn + nt * 16 + l15;              // C col = lane&15
                float val = acc[mt][nt][reg] + bias[gn];
                if (mode == 0) {
                    val *= 0.125f;   // 1/sqrt(DH)
                    long o = ((long)((gm >> 10) * 16 + (gn >> 6)) << 16) + ((gm & 1023) << 6) + (gn & 63);
                    ob[o] = f2bf(val);
                } else if (mode == 1) {
                    long o = ((long)((gm >> 10) * 16 + (gn >> 6)) << 16) + ((gm & 1023) << 6) + (gn & 63);
                    ob[o] = f2bf(val);
                } else if (mode == 2) {
                    long o = ((long)((gm >> 10) * 16 + (gn >> 6)) << 16) + ((long)(gn & 63) << 10) + (gm & 1023);
                    ob[o] = f2bf(val);
                } else {
                    ofp[(long)gm * 1024 + gn] = val;
                }
            }
}

// ---------------- Gc skewed GEMM -> SKEW-SPACE table Bskew ------------------
// Bskew[u][cc] = q[u] . emb[1024 + i_u + cc] + (cc<=i_u ? rpb[cc+2047] : rpb[cc+1022])
// (i_u = u & 1023, cc in [0,1023]).  Consumed by flash:
//   j <= i   : rel+rpb = Bskew[i][i-j]
//   j == i+1 : rel+rpb = rpb[2046]
//   j >= i+2 : rel+rpb = Bskew[i+1][i+1025-j]
__global__ __launch_bounds__(256) void gc_kernel(
    const u16* __restrict__ qb, const u16* __restrict__ embb,
    const float* __restrict__ rpb, u16* __restrict__ Bskew)
{
    int u0 = blockIdx.x * 32;
    int i0 = u0 & 1023;
    int t = threadIdx.x, lane = t & 63, wid = t >> 6;
    int l15 = lane & 15, quad = lane >> 4;

    __shared__ float lds_rpb[2048];   // [cc]=rpb[cc+2047], [1024+cc]=rpb[cc+1022]
    for (int j = t; j < 1024; j += 256) {
        lds_rpb[j] = rpb[j + 2047];
        lds_rpb[1024 + j] = rpb[j + 1022];
    }
    __syncthreads();

    // A fragments: rows u0 .. u0+31 (2 row-groups of 16)
    u16x8 aq[2][2];
#pragma unroll
    for (int rg = 0; rg < 2; rg++) {
        long qoff = (long)(u0 + rg * 16 + l15) * 64 + quad * 8;
        aq[rg][0] = *(const u16x8*)&qb[qoff];
        aq[rg][1] = *(const u16x8*)&qb[qoff + 32];
    }

    // prefetch first emb tile for this wave
    u16x8 nb0, nb1;
    {
        long ebase = (long)(1024 + i0 + wid * 16 + l15) * 64 + quad * 8;
        nb0 = *(const u16x8*)&embb[ebase];
        nb1 = *(const u16x8*)&embb[ebase + 32];
    }

    // w-tiles 0..65 cover w in [0,1056); max needed w = 1023+31 = 1054
    for (int tt = wid; tt < 66; tt += 4) {
        u16x8 b0 = nb0, b1 = nb1;
        if (tt + 4 < 66) {
            long ebase = (long)(1024 + i0 + (tt + 4) * 16 + l15) * 64 + quad * 8;
            nb0 = *(const u16x8*)&embb[ebase];
            nb1 = *(const u16x8*)&embb[ebase + 32];
        }
        int w0 = tt * 16;
#pragma unroll
        for (int rg = 0; rg < 2; rg++) {
            f32x4 c = {};
            c = mfma16(aq[rg][0], b0, c);
            c = mfma16(aq[rg][1], b1, c);
#pragma unroll
            for (int reg = 0; reg < 4; reg++) {
                int row = rg * 16 + quad * 4 + reg;
                int cc = w0 + l15 - row;
                if ((unsigned)cc <= 1023u) {
                    int i = i0 + row;
                    float rb = lds_rpb[cc + ((cc <= i) ? 0 : 1024)];
                    Bskew[((long)(u0 + row) << 10) + cc] = f2bf(c[reg] + rb);
                }
            }
        }
    }
}

// ---------------- flash attention (j-split x2, dbuf K/V @ 40960B LDS) -------
// r10/r12-verified structure (47.4-48.7us, 0 bank conflicts, clean traffic).
// Double-buffered K/V (32KB) + swizzled un-padded lds_p (8KB) = exactly 40960B.
// Tiles [64 rows][64 u16], chunk (8 u16) swizzle: pos p = c ^ (row&7);
// lds_p element (row,c) stored at row*64 + ((c>>3)^(row&7))*8 + (c&7).
__global__ __launch_bounds__(256, 4) void flash_kernel(
    const u16* __restrict__ qb, const u16* __restrict__ kb, const u16* __restrict__ vT,
    const u16* __restrict__ Bskew, const float* __restrict__ rpb,
    float* __restrict__ Po, float* __restrict__ Pm, float* __restrict__ Pl)
{
    int itile = blockIdx.x;        // 0..15
    int bh = blockIdx.y;           // 0..31
    int js = blockIdx.z;           // 0..1
    int t = threadIdx.x, lane = t & 63, wid = t >> 6;
    int l15 = lane & 15, quad = lane >> 4;
    int i0w = itile * 64 + wid * 16;

    __shared__ u16 lds_k[2][64 * 64];  // [j][d]
    __shared__ u16 lds_v[2][64 * 64];  // [d][j]
    __shared__ u16 lds_p[4][1024];     // per-wave P, chunk-swizzled, no pad

    int sr8 = lane >> 3, sp8 = lane & 7;   // staging: 8 rows x 8 chunks per instr

    float rpb2046 = rpb[2046];

    u16x8 aq[2];
    {
        long qoff = ((long)(bh * 1024) + i0w + l15) * 64 + quad * 8;
        aq[0] = *(const u16x8*)&qb[qoff];
        aq[1] = *(const u16x8*)&qb[qoff + 32];
    }
    float m_r[4], l_r[4];
    f32x4 o_acc[4] = {};
#pragma unroll
    for (int r = 0; r < 4; r++) { m_r[r] = -1e30f; l_r[r] = 0.f; }

    const u16* kbase = kb + (long)bh * 65536;
    const u16* vbase = vT + (long)bh * 65536;
    const u16* bbase = Bskew + ((long)bh << 20);

    auto stage = [&](int buf, int j0) {
#pragma unroll
        for (int q = 0; q < 2; q++) {
            int r = wid * 16 + q * 8 + sr8;
            int c = sp8 ^ (r & 7);
            gl2lds(kbase + (long)(j0 + r) * 64 + c * 8, &lds_k[buf][(wid * 16 + q * 8) * 64]);
            gl2lds(vbase + (long)r * 1024 + j0 + c * 8, &lds_v[buf][(wid * 16 + q * 8) * 64]);
        }
    };

    stage(0, js * 512);
    __syncthreads();   // vmcnt(0) drained: buf0 ready
    int cur = 0;

#pragma unroll 1
    for (int jt = 0; jt < 8; jt++) {
        int j0 = js * 512 + jt * 64;
        if (jt < 7) stage(cur ^ 1, j0 + 64);   // in flight across the whole compute phase

        // S = q @ k^T  (16 rows x 64 cols per wave)
        f32x4 s_acc[4];
#pragma unroll
        for (int nt = 0; nt < 4; nt++) {
            int r = nt * 16 + l15;
            u16x8 b0 = *(const u16x8*)&lds_k[cur][r * 64 + ((quad ^ (r & 7)) * 8)];
            u16x8 b1 = *(const u16x8*)&lds_k[cur][r * 64 + (((quad + 4) ^ (r & 7)) * 8)];
            f32x4 c = {};
            c = mfma16(aq[0], b0, c);
            c = mfma16(aq[1], b1, c);
            s_acc[nt] = c;
        }

        // + rel+rpb from skew-space table (wave-uniform tile classification, inline)
#pragma unroll
        for (int nt = 0; nt < 4; nt++) {
            int jn0 = j0 + nt * 16;
            int jj = jn0 + l15;
            if (jn0 + 15 <= i0w) {
#pragma unroll
                for (int reg = 0; reg < 4; reg++) {
                    int ii = i0w + quad * 4 + reg;
                    s_acc[nt][reg] += bf2f(bbase[((long)ii << 10) + (ii - jj)]);
                }
            } else if (jn0 >= i0w + 17) {
#pragma unroll
                for (int reg = 0; reg < 4; reg++) {
                    int ii = i0w + quad * 4 + reg;
                    s_acc[nt][reg] += bf2f(bbase[((long)(ii + 1) << 10) + (ii + 1025 - jj)]);
                }
            } else {
#pragma unroll
                for (int reg = 0; reg < 4; reg++) {
                    int ii = i0w + quad * 4 + reg;
                    float a;
                    if (jj <= ii)          a = bf2f(bbase[((long)ii << 10) + (ii - jj)]);
                    else if (jj == ii + 1) a = rpb2046;
                    else                   a = bf2f(bbase[((long)(ii + 1) << 10) + (ii + 1025 - jj)]);
                    s_acc[nt][reg] += a;
                }
            }
        }

        // online softmax (rows at quad*4+reg, 16 lanes per row-group)
#pragma unroll
        for (int reg = 0; reg < 4; reg++) {
            float mx = fmaxf(fmaxf(s_acc[0][reg], s_acc[1][reg]), fmaxf(s_acc[2][reg], s_acc[3][reg]));
            for (int off = 1; off < 16; off <<= 1) mx = fmaxf(mx, __shfl_xor(mx, off, 64));
            float mnew = fmaxf(m_r[reg], mx);
            float alpha = __expf(m_r[reg] - mnew);
            float rs = 0.f;
#pragma unroll
            for (int nt = 0; nt < 4; nt++) {
                float p = __expf(s_acc[nt][reg] - mnew);
                s_acc[nt][reg] = p;
                rs += p;
            }
            for (int off = 1; off < 16; off <<= 1) rs += __shfl_xor(rs, off, 64);
            l_r[reg] = l_r[reg] * alpha + rs;
            m_r[reg] = mnew;
#pragma unroll
            for (int dt = 0; dt < 4; dt++) o_acc[dt][reg] *= alpha;
        }

        // P: C-layout -> LDS (chunk-swizzled) -> A-layout (same wave, no barrier)
#pragma unroll
        for (int nt = 0; nt < 4; nt++)
#pragma unroll
            for (int reg = 0; reg < 4; reg++) {
                int row = quad * 4 + reg;
                int pos = ((nt * 2 + (l15 >> 3)) ^ (row & 7)) * 8 + (l15 & 7);
                lds_p[wid][row * 64 + pos] = f2bf(s_acc[nt][reg]);
            }

        u16x8 pf0 = *(const u16x8*)&lds_p[wid][l15 * 64 + ((quad ^ (l15 & 7)) * 8)];
        u16x8 pf1 = *(const u16x8*)&lds_p[wid][l15 * 64 + (((quad + 4) ^ (l15 & 7)) * 8)];
#pragma unroll
        for (int dt = 0; dt < 4; dt++) {
            int r = dt * 16 + l15;
            u16x8 v0 = *(const u16x8*)&lds_v[cur][r * 64 + ((quad ^ (r & 7)) * 8)];
            u16x8 v1 = *(const u16x8*)&lds_v[cur][r * 64 + (((quad + 4) ^ (r & 7)) * 8)];
            o_acc[dt] = mfma16(pf0, v0, o_acc[dt]);
            o_acc[dt] = mfma16(pf1, v1, o_acc[dt]);
        }

        __syncthreads();   // all waves done with [cur]; drains staged loads for [cur^1]
        cur ^= 1;
    }

    int blk = (js * 32 + bh) * 16 + itile;
    float* PoB = Po + (long)blk * 4096;
#pragma unroll
    for (int dt = 0; dt < 4; dt++)
#pragma unroll
        for (int reg = 0; reg < 4; reg++) {
            int rr = wid * 16 + quad * 4 + reg;
            PoB[rr * 64 + dt * 16 + l15] = o_acc[dt][reg];
        }
    if (l15 == 0) {
#pragma unroll
        for (int reg = 0; reg < 4; reg++) {
            int rr = wid * 16 + quad * 4 + reg;
            Pm[blk * 64 + rr] = m_r[reg];
            Pl[blk * 64 + rr] = l_r[reg];
        }
    }
}

// ---------------- combine the 2 j-partials -> attn (bf16 [B,S,E]) -----------
__global__ __launch_bounds__(256) void combine_kernel(
    const float* __restrict__ Po, const float* __restrict__ Pm, const float* __restrict__ Pl,
    u16* __restrict__ attn)
{
    int itile = blockIdx.x, bh = blockIdx.y;
    int t = threadIdx.x;
    int c = t & 63, rg = t >> 6;
    int blk0 = bh * 16 + itile;
    int blk1 = (32 + bh) * 16 + itile;
    int b = bh >> 4, h = bh & 15;
    for (int rr = rg; rr < 64; rr += 4) {
        float m0 = Pm[blk0 * 64 + rr], m1 = Pm[blk1 * 64 + rr];
        float ms = fmaxf(m0, m1);
        float e0 = __expf(m0 - ms), e1 = __expf(m1 - ms);
        float l = Pl[blk0 * 64 + rr] * e0 + Pl[blk1 * 64 + rr] * e1;
        float o = Po[(long)blk0 * 4096 + rr * 64 + c] * e0
                + Po[(long)blk1 * 4096 + rr * 64 + c] * e1;
        int ii = itile * 64 + rr;
        attn[((long)(b * 1024 + ii)) * 1024 + h * 64 + c] = f2bf(o / l);
    }
}

// ---------------------------------------------------------------------------
extern "C" void kernel_launch(void* const* d_in, const int* in_sizes, int n_in,
                              void* d_out, int out_size, void* d_ws, size_t ws_size,
                              hipStream_t stream)
{
    const float* query = (const float*)d_in[0];
    const float* key_  = (const float*)d_in[1];
    const float* value = (const float*)d_in[2];
    const float* Wq = (const float*)d_in[3];
    const float* bq = (const float*)d_in[4];
    const float* Wk = (const float*)d_in[5];
    const float* bk = (const float*)d_in[6];
    const float* Wv = (const float*)d_in[7];
    const float* bv = (const float*)d_in[8];
    const float* Wo = (const float*)d_in[9];
    const float* bo = (const float*)d_in[10];
    const float* emb = (const float*)d_in[11];
    const float* rpb = (const float*)d_in[12];

    char* ws = (char*)d_ws;
    // live whole pipeline / early phase:
    u16* xq   = (u16*)(ws + 0);          // 4 MB   (dead after QKV gemm)
    u16* xk   = (u16*)(ws + 4194304);    // 4 MB   (dead after QKV gemm)
    u16* xv   = (u16*)(ws + 8388608);    // 4 MB   (dead after QKV gemm)
    u16* WqT  = (u16*)(ws + 12582912);   // 2 MB   (dead after QKV gemm)
    u16* WkT  = (u16*)(ws + 14680064);   // 2 MB   (dead after QKV gemm)
    u16* WvT  = (u16*)(ws + 16777216);   // 2 MB   (dead after QKV gemm)
    u16* embb = (u16*)(ws + 18874368);   // 512 KB (dead after gc)
    u16* WoT  = (u16*)(ws + 19922944);   // 2 MB   (live till final gemm)
    u16* qb   = (u16*)(ws + 22020096);   // 4 MB   (dead after flash)
    u16* kb   = (u16*)(ws + 26214400);   // 4 MB
    u16* vT   = (u16*)(ws + 30408704);   // 4 MB
    u16* Bskew= (u16*)(ws + 34603008);   // 64 MB -> ends 101711872
    // overlays (regions dead by the time these are written):
    float* Po = (float*)(ws + 0);          // 16 MB over xq/xk/xv/WqT/WkT
    float* Pm = (float*)(ws + 16777216);   // 256 KB over WvT
    float* Pl = (float*)(ws + 17039360);   // 256 KB over WvT
    u16* attn = (u16*)(ws + 22020096);     // 4 MB over qb

    cvtwt_kernel<<<7424, 256, 0, stream>>>(query, key_, value, emb, Wq, Wk, Wv, Wo,
                                           xq, xk, xv, embb, WqT, WkT, WvT, WoT);
    gemm_kernel<2><<<dim3(8, 32, 3), 256, 0, stream>>>(xq, xk, xv, WqT, WkT, WvT,
                                                       bq, bk, bv, qb, kb, vT, nullptr, 0);
    gc_kernel<<<1024, 256, 0, stream>>>(qb, embb, rpb, Bskew);
    flash_kernel<<<dim3(16, 32, 2), 256, 0, stream>>>(qb, kb, vT, Bskew, rpb, Po, Pm, Pl);
    combine_kernel<<<dim3(16, 32), 256, 0, stream>>>(Po, Pm, Pl, attn);
    gemm_kernel<1><<<dim3(8, 64, 1), 256, 0, stream>>>(attn, nullptr, nullptr, WoT, nullptr, nullptr,
                                                       bo, nullptr, nullptr,
                                                       nullptr, nullptr, nullptr, (float*)d_out, 3);
}